// Round 3
// baseline (435.714 us; speedup 1.0000x reference)
//
#include <hip/hip_runtime.h>
#include <hip/hip_bf16.h>
#include <math.h>

typedef __attribute__((ext_vector_type(8))) short short8;
typedef __attribute__((ext_vector_type(4))) float f32x4;

__device__ inline unsigned short f2bf(float x) {
    union { float f; unsigned u; } v; v.f = x;
    unsigned r = v.u + 0x7fff + ((v.u >> 16) & 1);
    return (unsigned short)(r >> 16);
}

// ---------------- projection + L2 normalize (f32 compute, bf16 out) ----------------
// src [M][768] @ W [768][128] + b -> normalize rows -> dst bf16 [M][128]
__global__ __launch_bounds__(256) void proj_norm_kernel(
    const float* __restrict__ src, const float* __restrict__ Wm,
    const float* __restrict__ bias, unsigned short* __restrict__ dst)
{
    __shared__ float As[32][20];   // pad 16->20 keeps float4 alignment (80B rows)
    __shared__ float Bs[16][128];
    const int tid = threadIdx.x;
    const int m0 = blockIdx.x * 32;
    const int ig = tid >> 5;   // 0..7: rows ig*4..ig*4+3
    const int jg = tid & 31;   // 0..31: cols jg*4..jg*4+3

    float acc[4][4];
#pragma unroll
    for (int r = 0; r < 4; ++r)
#pragma unroll
        for (int c = 0; c < 4; ++c) acc[r][c] = 0.f;

    const int ra = tid >> 3, ka = (tid & 7) * 2;
    const int rb = tid >> 4, cb = (tid & 15) * 8;

    for (int k0 = 0; k0 < 768; k0 += 16) {
        const float2 av = *reinterpret_cast<const float2*>(
            src + (size_t)(m0 + ra) * 768 + k0 + ka);
        As[ra][ka] = av.x; As[ra][ka + 1] = av.y;
        const float4* wp = reinterpret_cast<const float4*>(
            Wm + (size_t)(k0 + rb) * 128 + cb);
        *reinterpret_cast<float4*>(&Bs[rb][cb]) = wp[0];
        *reinterpret_cast<float4*>(&Bs[rb][cb + 4]) = wp[1];
        __syncthreads();
#pragma unroll
        for (int kq = 0; kq < 16; kq += 4) {
            float4 b0 = *reinterpret_cast<const float4*>(&Bs[kq + 0][jg * 4]);
            float4 b1 = *reinterpret_cast<const float4*>(&Bs[kq + 1][jg * 4]);
            float4 b2 = *reinterpret_cast<const float4*>(&Bs[kq + 2][jg * 4]);
            float4 b3 = *reinterpret_cast<const float4*>(&Bs[kq + 3][jg * 4]);
#pragma unroll
            for (int r = 0; r < 4; ++r) {
                float4 a = *reinterpret_cast<const float4*>(&As[ig * 4 + r][kq]);
                acc[r][0] += a.x * b0.x + a.y * b1.x + a.z * b2.x + a.w * b3.x;
                acc[r][1] += a.x * b0.y + a.y * b1.y + a.z * b2.y + a.w * b3.y;
                acc[r][2] += a.x * b0.z + a.y * b1.z + a.z * b2.z + a.w * b3.z;
                acc[r][3] += a.x * b0.w + a.y * b1.w + a.z * b2.w + a.w * b3.w;
            }
        }
        __syncthreads();
    }

    const float4 bb = *reinterpret_cast<const float4*>(bias + jg * 4);
#pragma unroll
    for (int r = 0; r < 4; ++r) {
        acc[r][0] += bb.x; acc[r][1] += bb.y; acc[r][2] += bb.z; acc[r][3] += bb.w;
        float ss = acc[r][0] * acc[r][0] + acc[r][1] * acc[r][1]
                 + acc[r][2] * acc[r][2] + acc[r][3] * acc[r][3];
#pragma unroll
        for (int msk = 16; msk >= 1; msk >>= 1) ss += __shfl_xor(ss, msk);
        const float inv = 1.0f / fmaxf(sqrtf(ss), 1e-12f);
        ushort4 o;
        o.x = f2bf(acc[r][0] * inv);
        o.y = f2bf(acc[r][1] * inv);
        o.z = f2bf(acc[r][2] * inv);
        o.w = f2bf(acc[r][3] * inv);
        *reinterpret_cast<ushort4*>(dst + (size_t)(m0 + ig * 4 + r) * 128 + jg * 4) = o;
    }
}

// ---------------- maxsim via bf16 MFMA ----------------
// block = (t, group of 16 labels); 4 waves, wave w owns text rows [w*64, w*64+64)
__global__ __launch_bounds__(256) void maxsim_kernel(
    const unsigned short* __restrict__ temb,  // [32768][128] bf16
    const unsigned short* __restrict__ lemb,  // [4096][128] bf16
    const int* __restrict__ tmask,            // [128][256]
    const int* __restrict__ lmask,            // [128][32]
    const float* __restrict__ scale_p,
    float* __restrict__ logits)               // [128][128]
{
    const int t = blockIdx.x;
    const int lg = blockIdx.y;
    const int tid = threadIdx.x;
    const int lane = tid & 63;
    const int w = tid >> 6;
    const int lq = lane >> 4;   // 0..3
    const int lr = lane & 15;   // 0..15
    const short* tp = reinterpret_cast<const short*>(temb);
    const short* lp = reinterpret_cast<const short*>(lemb);

    // A fragments: rows = text tokens (held for the whole 16-label loop)
    short8 afr[4][4];
#pragma unroll
    for (int m = 0; m < 4; ++m)
#pragma unroll
        for (int kc = 0; kc < 4; ++kc)
            afr[m][kc] = *reinterpret_cast<const short8*>(
                tp + (size_t)(t * 256 + w * 64 + m * 16 + lr) * 128 + kc * 32 + lq * 8);

    // text-mask bits for this lane's 16 accumulator rows
    unsigned mb = 0;
#pragma unroll
    for (int m = 0; m < 4; ++m)
#pragma unroll
        for (int i2 = 0; i2 < 4; ++i2) {
            int s = w * 64 + m * 16 + lq * 4 + i2;
            if (tmask[t * 256 + s]) mb |= 1u << (m * 4 + i2);
        }

    __shared__ float red[4][32];
    const float scale = *scale_p;
    const float NEGINF = -__builtin_inff();

    for (int li = 0; li < 16; ++li) {
        const int l = lg * 16 + li;
        short8 bfr[2][4];
#pragma unroll
        for (int n = 0; n < 2; ++n)
#pragma unroll
            for (int kc = 0; kc < 4; ++kc)
                bfr[n][kc] = *reinterpret_cast<const short8*>(
                    lp + (size_t)(l * 32 + n * 16 + lr) * 128 + kc * 32 + lq * 8);

        f32x4 acc[4][2];
#pragma unroll
        for (int m = 0; m < 4; ++m)
#pragma unroll
            for (int n = 0; n < 2; ++n) acc[m][n] = (f32x4)(0.f);
#pragma unroll
        for (int kc = 0; kc < 4; ++kc)
#pragma unroll
            for (int m = 0; m < 4; ++m)
#pragma unroll
                for (int n = 0; n < 2; ++n)
                    acc[m][n] = __builtin_amdgcn_mfma_f32_16x16x32_bf16(
                        afr[m][kc], bfr[n][kc], acc[m][n], 0, 0, 0);

        // masked max over this wave's 64 text rows, per column (label token)
        float mx0 = NEGINF, mx1 = NEGINF;
#pragma unroll
        for (int m = 0; m < 4; ++m)
#pragma unroll
            for (int i2 = 0; i2 < 4; ++i2) {
                if ((mb >> (m * 4 + i2)) & 1u) {
                    mx0 = fmaxf(mx0, acc[m][0][i2]);
                    mx1 = fmaxf(mx1, acc[m][1][i2]);
                }
            }
        mx0 = fmaxf(mx0, __shfl_xor(mx0, 16));
        mx0 = fmaxf(mx0, __shfl_xor(mx0, 32));
        mx1 = fmaxf(mx1, __shfl_xor(mx1, 16));
        mx1 = fmaxf(mx1, __shfl_xor(mx1, 32));
        if (lq == 0) { red[w][lr] = mx0; red[w][16 + lr] = mx1; }
        __syncthreads();

        if (tid < 32) {
            float m4 = fmaxf(fmaxf(red[0][tid], red[1][tid]),
                             fmaxf(red[2][tid], red[3][tid]));
            const int lmv = lmask[l * 32 + tid];
            float val = lmv ? m4 : 0.0f;
            float cnt = lmv ? 1.0f : 0.0f;
#pragma unroll
            for (int msk = 16; msk >= 1; msk >>= 1) {
                val += __shfl_xor(val, msk);
                cnt += __shfl_xor(cnt, msk);
            }
            if (tid == 0) logits[t * 128 + l] = scale * val / fmaxf(cnt, 1.0f);
        }
        __syncthreads();
    }
}

// ---------------- BCE + sigmoid ----------------
__global__ __launch_bounds__(256) void finalize_kernel(
    const float* __restrict__ logits, const float* __restrict__ targets,
    float* __restrict__ out)
{
    const int tid = threadIdx.x;
    float sum = 0.f;
    for (int i = tid; i < 16384; i += 256) {
        const float x = logits[i];
        const float tg = targets[i];
        out[1 + i] = 1.0f / (1.0f + expf(-x));
        sum += fmaxf(x, 0.f) - x * tg + log1pf(expf(-fabsf(x)));
    }
    __shared__ float part[4];
#pragma unroll
    for (int msk = 32; msk >= 1; msk >>= 1) sum += __shfl_xor(sum, msk);
    if ((tid & 63) == 0) part[tid >> 6] = sum;
    __syncthreads();
    if (tid == 0)
        out[0] = (part[0] + part[1] + part[2] + part[3]) * (1.0f / 16384.0f);
}

extern "C" void kernel_launch(void* const* d_in, const int* in_sizes, int n_in,
                              void* d_out, int out_size, void* d_ws, size_t ws_size,
                              hipStream_t stream) {
    const float* text_hidden  = (const float*)d_in[0];
    const float* label_hidden = (const float*)d_in[1];
    const int*   text_mask    = (const int*)d_in[2];
    const int*   label_mask   = (const int*)d_in[3];
    const float* targets      = (const float*)d_in[4];
    const float* W_proj       = (const float*)d_in[5];
    const float* b_proj       = (const float*)d_in[6];
    const float* score_scale  = (const float*)d_in[7];
    float* out = (float*)d_out;

    char* ws = (char*)d_ws;
    unsigned short* temb = (unsigned short*)ws;                          // 32768*128*2 = 8 MB
    unsigned short* lemb = (unsigned short*)(ws + 8388608);              // 4096*128*2  = 1 MB
    float* logits        = (float*)(ws + 8388608 + 1048576);             // 16384*4

    proj_norm_kernel<<<1024, 256, 0, stream>>>(text_hidden,  W_proj, b_proj, temb);
    proj_norm_kernel<<<128,  256, 0, stream>>>(label_hidden, W_proj, b_proj, lemb);
    maxsim_kernel<<<dim3(128, 8), 256, 0, stream>>>(temb, lemb, text_mask, label_mask,
                                                    score_scale, logits);
    finalize_kernel<<<1, 256, 0, stream>>>(logits, targets, out);
}

// Round 5
// 375.271 us; speedup vs baseline: 1.1611x; 1.1611x over previous
//
#include <hip/hip_runtime.h>
#include <hip/hip_bf16.h>
#include <math.h>

typedef __attribute__((ext_vector_type(8))) short short8;
typedef __attribute__((ext_vector_type(4))) float f32x4;

__device__ inline unsigned short f2bf(float x) {
    union { float f; unsigned u; } v; v.f = x;
    unsigned r = v.u + 0x7fff + ((v.u >> 16) & 1);
    return (unsigned short)(r >> 16);
}
__device__ inline float bf2f(unsigned short h) {
    union { unsigned u; float f; } v; v.u = ((unsigned)h) << 16;
    return v.f;
}

// ---------------- W prep: transpose [768][128] f32 -> [128][768] bf16 hi/lo ----------------
__global__ __launch_bounds__(256) void prep_w_kernel(
    const float* __restrict__ Wm, unsigned short* __restrict__ wht,
    unsigned short* __restrict__ wlt)
{
    const int tid = threadIdx.x;
    const int n = tid & 127;
    const int kg = tid >> 7;                 // 0..1
    const int k0 = blockIdx.x * 32 + kg * 16;
    short8 hi0, hi1, lo0, lo1;
#pragma unroll
    for (int j = 0; j < 16; ++j) {
        const float wv = Wm[(size_t)(k0 + j) * 128 + n];
        const unsigned short h = f2bf(wv);
        const unsigned short l = f2bf(wv - bf2f(h));
        if (j < 8) { hi0[j] = (short)h; lo0[j] = (short)l; }
        else       { hi1[j - 8] = (short)h; lo1[j - 8] = (short)l; }
    }
    short* whp = reinterpret_cast<short*>(wht) + (size_t)n * 768 + k0;
    short* wlp = reinterpret_cast<short*>(wlt) + (size_t)n * 768 + k0;
    *reinterpret_cast<short8*>(whp) = hi0;
    *reinterpret_cast<short8*>(whp + 8) = hi1;
    *reinterpret_cast<short8*>(wlp) = lo0;
    *reinterpret_cast<short8*>(wlp + 8) = lo1;
}

// ---------------- projection via split-bf16 MFMA + L2 norm + mask-zeroing ----------------
// block = 4 waves x 32 rows = 128 rows. Wave: 2 m-frags x 8 n-frags, K=768 (24 kc).
// C = (ah+al)@(wh+wl) ~= ah@wh + al@wh + ah@wl  (error ~2^-17, f32-equivalent)
__global__ __launch_bounds__(256, 2) void proj_mfma_kernel(
    const float* __restrict__ src, const unsigned short* __restrict__ wht,
    const unsigned short* __restrict__ wlt, const float* __restrict__ bias,
    const int* __restrict__ mask, unsigned short* __restrict__ dst)
{
    const int tid = threadIdx.x;
    const int lane = tid & 63, w = tid >> 6;
    const int lq = lane >> 4, lr = lane & 15;
    const int rbase = blockIdx.x * 128 + w * 32;

    f32x4 acc[2][8];
#pragma unroll
    for (int m = 0; m < 2; ++m)
#pragma unroll
        for (int n = 0; n < 8; ++n) acc[m][n] = (f32x4)(0.f);

    float bb[8];
#pragma unroll
    for (int n = 0; n < 8; ++n) bb[n] = bias[n * 16 + lr];

    const float* ap0 = src + (size_t)(rbase + lr) * 768 + lq * 8;        // m=0
    const float* ap1 = src + (size_t)(rbase + 16 + lr) * 768 + lq * 8;   // m=1
    const short* whp = reinterpret_cast<const short*>(wht) + (size_t)lr * 768 + lq * 8;
    const short* wlp = reinterpret_cast<const short*>(wlt) + (size_t)lr * 768 + lq * 8;

    for (int kc = 0; kc < 24; ++kc) {
        short8 ah[2], al[2];
#pragma unroll
        for (int m = 0; m < 2; ++m) {
            const float* ap = (m == 0 ? ap0 : ap1) + kc * 32;
            f32x4 a0 = *reinterpret_cast<const f32x4*>(ap);
            f32x4 a1 = *reinterpret_cast<const f32x4*>(ap + 4);
#pragma unroll
            for (int j = 0; j < 8; ++j) {
                const float av = (j < 4) ? a0[j] : a1[j - 4];
                const unsigned short h = f2bf(av);
                const unsigned short l = f2bf(av - bf2f(h));
                ah[m][j] = (short)h; al[m][j] = (short)l;
            }
        }
        short8 wh[8];
#pragma unroll
        for (int n = 0; n < 8; ++n)
            wh[n] = *reinterpret_cast<const short8*>(whp + (size_t)n * 16 * 768 + kc * 32);
#pragma unroll
        for (int m = 0; m < 2; ++m)
#pragma unroll
            for (int n = 0; n < 8; ++n)
                acc[m][n] = __builtin_amdgcn_mfma_f32_16x16x32_bf16(ah[m], wh[n], acc[m][n], 0, 0, 0);
#pragma unroll
        for (int m = 0; m < 2; ++m)
#pragma unroll
            for (int n = 0; n < 8; ++n)
                acc[m][n] = __builtin_amdgcn_mfma_f32_16x16x32_bf16(al[m], wh[n], acc[m][n], 0, 0, 0);
        short8 wl[8];
#pragma unroll
        for (int n = 0; n < 8; ++n)
            wl[n] = *reinterpret_cast<const short8*>(wlp + (size_t)n * 16 * 768 + kc * 32);
#pragma unroll
        for (int m = 0; m < 2; ++m)
#pragma unroll
            for (int n = 0; n < 8; ++n)
                acc[m][n] = __builtin_amdgcn_mfma_f32_16x16x32_bf16(ah[m], wl[n], acc[m][n], 0, 0, 0);
    }

    // epilogue: bias, row L2 norm (rows spread over lq*4+i2), mask-zero, bf16 store
#pragma unroll
    for (int m = 0; m < 2; ++m) {
#pragma unroll
        for (int n = 0; n < 8; ++n)
#pragma unroll
            for (int i2 = 0; i2 < 4; ++i2) acc[m][n][i2] += bb[n];
        float ss[4];
#pragma unroll
        for (int i2 = 0; i2 < 4; ++i2) {
            float s = 0.f;
#pragma unroll
            for (int n = 0; n < 8; ++n) s += acc[m][n][i2] * acc[m][n][i2];
            s += __shfl_xor(s, 1); s += __shfl_xor(s, 2);
            s += __shfl_xor(s, 4); s += __shfl_xor(s, 8);
            ss[i2] = s;
        }
#pragma unroll
        for (int i2 = 0; i2 < 4; ++i2) {
            const int row = rbase + m * 16 + lq * 4 + i2;
            float inv = 1.0f / fmaxf(sqrtf(ss[i2]), 1e-12f);
            if (mask[row] == 0) inv = 0.f;   // fold mask into embedding (zeroed rows)
#pragma unroll
            for (int n = 0; n < 8; ++n)
                dst[(size_t)row * 128 + n * 16 + lr] = f2bf(acc[m][n][i2] * inv);
        }
    }
}

// ---------------- maxsim: barrier-free, wave = 4 labels x 256 text rows ----------------
// Masks pre-folded: masked text rows -> sim 0 (never wins max, true colmax > 0 w.p. 1);
// masked label cols -> colmax exactly 0 -> drop out of the sum.
__global__ __launch_bounds__(256, 2) void maxsim_kernel(
    const unsigned short* __restrict__ temb,  // [32768][128] bf16
    const unsigned short* __restrict__ lemb,  // [4096][128] bf16
    float* __restrict__ sums)                 // [128][128] raw col-max sums
{
    const int t = blockIdx.x;                 // grid (128,8): wgid%8 = t%8 -> XCD locality
    const int bg = blockIdx.y;
    const int tid = threadIdx.x;
    const int lane = tid & 63, w = tid >> 6;
    const int lq = lane >> 4, lr = lane & 15;
    const short* tp = reinterpret_cast<const short*>(temb);
    const short* lp = reinterpret_cast<const short*>(lemb);
    const int l0 = bg * 16 + w * 4;           // this wave's first label

    short8 bfr[8][4];
#pragma unroll
    for (int n = 0; n < 8; ++n)
#pragma unroll
        for (int kc = 0; kc < 4; ++kc)
            bfr[n][kc] = *reinterpret_cast<const short8*>(
                lp + (size_t)(l0 * 32 + n * 16 + lr) * 128 + kc * 32 + lq * 8);

    f32x4 cmx[8];
#pragma unroll
    for (int n = 0; n < 8; ++n) cmx[n] = (f32x4)(-1e30f);

    const short* ap0 = tp + (size_t)(t * 256 + lr) * 128 + lq * 8;

    for (int m = 0; m < 16; ++m) {
        short8 afr[4];
#pragma unroll
        for (int kc = 0; kc < 4; ++kc)
            afr[kc] = *reinterpret_cast<const short8*>(ap0 + (size_t)m * 16 * 128 + kc * 32);
        f32x4 acc[8];
#pragma unroll
        for (int n = 0; n < 8; ++n) acc[n] = (f32x4)(0.f);
#pragma unroll
        for (int kc = 0; kc < 4; ++kc)
#pragma unroll
            for (int n = 0; n < 8; ++n)
                acc[n] = __builtin_amdgcn_mfma_f32_16x16x32_bf16(afr[kc], bfr[n][kc], acc[n], 0, 0, 0);
#pragma unroll
        for (int n = 0; n < 8; ++n) {
            cmx[n][0] = fmaxf(cmx[n][0], acc[n][0]);
            cmx[n][1] = fmaxf(cmx[n][1], acc[n][1]);
            cmx[n][2] = fmaxf(cmx[n][2], acc[n][2]);
            cmx[n][3] = fmaxf(cmx[n][3], acc[n][3]);
        }
    }

    float s[8];
#pragma unroll
    for (int n = 0; n < 8; ++n) {
        float v = fmaxf(fmaxf(cmx[n][0], cmx[n][1]), fmaxf(cmx[n][2], cmx[n][3]));
        v = fmaxf(v, __shfl_xor(v, 16));      // max over lq (rows)
        v = fmaxf(v, __shfl_xor(v, 32));
        v += __shfl_xor(v, 1);                // sum over lr (16 cols of frag)
        v += __shfl_xor(v, 2);
        v += __shfl_xor(v, 4);
        v += __shfl_xor(v, 8);
        s[n] = v;
    }
    if (lane == 0) {
#pragma unroll
        for (int li = 0; li < 4; ++li)
            sums[t * 128 + l0 + li] = s[2 * li] + s[2 * li + 1];
    }
}

// ---------------- finalize: label counts + scale/mean + sigmoid + BCE ----------------
__global__ __launch_bounds__(256) void finalize_kernel(
    const float* __restrict__ sums, const int* __restrict__ lmask,
    const float* __restrict__ targets, const float* __restrict__ scale_p,
    float* __restrict__ out)
{
    __shared__ float cl[128];
    const int tid = threadIdx.x;
    if (tid < 128) {
        int c = 0;
#pragma unroll
        for (int r = 0; r < 32; ++r) c += lmask[tid * 32 + r];
        cl[tid] = fmaxf((float)c, 1.0f);
    }
    __syncthreads();
    const float scale = *scale_p;
    float sum = 0.f;
    for (int i = tid; i < 16384; i += 256) {
        const float x = scale * sums[i] / cl[i & 127];
        const float tg = targets[i];
        out[1 + i] = 1.0f / (1.0f + expf(-x));
        sum += fmaxf(x, 0.f) - x * tg + log1pf(expf(-fabsf(x)));
    }
    __shared__ float part[4];
#pragma unroll
    for (int msk = 32; msk >= 1; msk >>= 1) sum += __shfl_xor(sum, msk);
    if ((tid & 63) == 0) part[tid >> 6] = sum;
    __syncthreads();
    if (tid == 0)
        out[0] = (part[0] + part[1] + part[2] + part[3]) * (1.0f / 16384.0f);
}

extern "C" void kernel_launch(void* const* d_in, const int* in_sizes, int n_in,
                              void* d_out, int out_size, void* d_ws, size_t ws_size,
                              hipStream_t stream) {
    const float* text_hidden  = (const float*)d_in[0];
    const float* label_hidden = (const float*)d_in[1];
    const int*   text_mask    = (const int*)d_in[2];
    const int*   label_mask   = (const int*)d_in[3];
    const float* targets      = (const float*)d_in[4];
    const float* W_proj       = (const float*)d_in[5];
    const float* b_proj       = (const float*)d_in[6];
    const float* score_scale  = (const float*)d_in[7];
    float* out = (float*)d_out;

    char* ws = (char*)d_ws;
    unsigned short* temb = (unsigned short*)(ws);                    // 8 MB
    unsigned short* lemb = (unsigned short*)(ws + 8388608);          // 1 MB
    float*          sums = (float*)(ws + 9437184);                   // 64 KB
    unsigned short* wht  = (unsigned short*)(ws + 9502720);          // 192 KB
    unsigned short* wlt  = (unsigned short*)(ws + 9699328);          // 192 KB

    prep_w_kernel<<<24, 256, 0, stream>>>(W_proj, wht, wlt);
    proj_mfma_kernel<<<256, 256, 0, stream>>>(text_hidden, wht, wlt, b_proj,
                                              text_mask, temb);
    proj_mfma_kernel<<<32, 256, 0, stream>>>(label_hidden, wht, wlt, b_proj,
                                             label_mask, lemb);
    maxsim_kernel<<<dim3(128, 8), 256, 0, stream>>>(temb, lemb, sums);
    finalize_kernel<<<1, 256, 0, stream>>>(sums, label_mask, targets, score_scale, out);
}